// Round 2
// baseline (929.207 us; speedup 1.0000x reference)
//
#include <hip/hip_runtime.h>

typedef __bf16 bf16x8 __attribute__((ext_vector_type(8)));
typedef float f32x4 __attribute__((ext_vector_type(4)));
typedef unsigned short ushort_t;

__device__ __forceinline__ ushort_t f2bf(float f) {
  unsigned int u = __float_as_uint(f);
  u += 0x7fffu + ((u >> 16) & 1u);
  return (ushort_t)(u >> 16);
}

__global__ __launch_bounds__(256) void fill_k(float* __restrict__ p, long n, float v) {
  long i = (long)blockIdx.x * 256 + threadIdx.x;
  if (i < n) p[i] = v;
}

// ---------------- batched transpose: fp32 Z x R x C  ->  bf16 Z x C x R ----
__global__ __launch_bounds__(256) void transpose_w(const float* __restrict__ in,
                                                   ushort_t* __restrict__ out,
                                                   int R, int C) {
  __shared__ float tile[32][33];
  const float* inb = in + (long)blockIdx.z * R * C;
  ushort_t* outb = out + (long)blockIdx.z * R * C;
  int r0 = blockIdx.x * 32, c0 = blockIdx.y * 32;
  int tx = threadIdx.x & 31, ty = threadIdx.x >> 5;
#pragma unroll
  for (int i = ty; i < 32; i += 8) tile[i][tx] = inb[(long)(r0 + i) * C + (c0 + tx)];
  __syncthreads();
#pragma unroll
  for (int i = ty; i < 32; i += 8) outb[(long)(c0 + i) * R + (r0 + tx)] = f2bf(tile[tx][i]);
}

// ---------------- layernorm: one row (D=1024) per 256-thread block ---------
// In-place safe (outF may alias x): each thread reads its 4 elems before any write.
__global__ __launch_bounds__(256) void ln_k(const float* __restrict__ x,
                                            const float* __restrict__ g,
                                            const float* __restrict__ b,
                                            float* __restrict__ outF,
                                            ushort_t* __restrict__ outU) {
  __shared__ float red[8];
  long row = blockIdx.x;
  int tid = threadIdx.x;
  float4 v = ((const float4*)(x + row * 1024))[tid];
  float s = v.x + v.y + v.z + v.w;
#pragma unroll
  for (int off = 32; off; off >>= 1) s += __shfl_xor(s, off);
  int w = tid >> 6;
  if ((tid & 63) == 0) red[w] = s;
  __syncthreads();
  float mean = (red[0] + red[1] + red[2] + red[3]) * (1.0f / 1024.0f);
  float dx = v.x - mean, dy = v.y - mean, dz = v.z - mean, dw = v.w - mean;
  float s2 = dx * dx + dy * dy + dz * dz + dw * dw;
#pragma unroll
  for (int off = 32; off; off >>= 1) s2 += __shfl_xor(s2, off);
  if ((tid & 63) == 0) red[4 + w] = s2;
  __syncthreads();
  float var = (red[4] + red[5] + red[6] + red[7]) * (1.0f / 1024.0f);
  float rstd = rsqrtf(var + 1e-5f);
  int c = tid * 4;
  float o0 = dx * rstd * g[c + 0] + b[c + 0];
  float o1 = dy * rstd * g[c + 1] + b[c + 1];
  float o2 = dz * rstd * g[c + 2] + b[c + 2];
  float o3 = dw * rstd * g[c + 3] + b[c + 3];
  ((float4*)(outF + row * 1024))[tid] = make_float4(o0, o1, o2, o3);
  ushort4 u;
  u.x = f2bf(o0); u.y = f2bf(o1); u.z = f2bf(o2); u.w = f2bf(o3);
  ((ushort4*)(outU + row * 1024))[tid] = u;
}

// ---------------- bf16 GEMM: C(MxN) = A(MxK) * Bt(NxK)^T, fp32 accum -------
// 128x128 tile, BK=32, 256 threads = 4 waves in 2x2. Epilogues:
//  EPI 0: bf16 out in [b,h,t,e] layout (Q/K)
//  EPI 1: bf16 out in [b,h,e,t] layout (V transposed)
//  EPI 2: fp32 out = acc + bias[col] + res[row*N+col]   (proj->y, ff2->out)
//  EPI 3: bf16 out = relu(acc + bias[col])              (ff1)
template <int EPI>
__global__ __launch_bounds__(256) void gemm_bf16(const ushort_t* __restrict__ A,
                                                 const ushort_t* __restrict__ Bt,
                                                 int M, int N, int K,
                                                 const float* __restrict__ bias,
                                                 const float* res, float* outF,
                                                 ushort_t* __restrict__ outU) {
  __shared__ __align__(16) ushort_t As[128][40];
  __shared__ __align__(16) ushort_t Bs[128][40];
  const int tid = threadIdx.x;
  const int lane = tid & 63;
  const int w = tid >> 6;
  const int wr = w >> 1, wc = w & 1;
  const int g = lane >> 4, lr = lane & 15;
  const long m0 = (long)blockIdx.x * 128;
  const long n0 = (long)blockIdx.y * 128;
  const int sr = tid >> 1;           // staging row 0..127
  const int sk = (tid & 1) * 16;     // staging k offset 0 or 16
  const ushort_t* Ab = A + (m0 + sr) * K + sk;
  const ushort_t* Bb = Bt + (n0 + sr) * K + sk;
  f32x4 acc[4][4] = {};
  for (int k0 = 0; k0 < K; k0 += 32) {
    *(uint4*)&As[sr][sk + 0] = *(const uint4*)(Ab + k0 + 0);
    *(uint4*)&As[sr][sk + 8] = *(const uint4*)(Ab + k0 + 8);
    *(uint4*)&Bs[sr][sk + 0] = *(const uint4*)(Bb + k0 + 0);
    *(uint4*)&Bs[sr][sk + 8] = *(const uint4*)(Bb + k0 + 8);
    __syncthreads();
    bf16x8 fa[4], fb[4];
#pragma unroll
    for (int m = 0; m < 4; m++) fa[m] = *(const bf16x8*)&As[wr * 64 + m * 16 + lr][g * 8];
#pragma unroll
    for (int n = 0; n < 4; n++) fb[n] = *(const bf16x8*)&Bs[wc * 64 + n * 16 + lr][g * 8];
#pragma unroll
    for (int m = 0; m < 4; m++)
#pragma unroll
      for (int n = 0; n < 4; n++)
        acc[m][n] = __builtin_amdgcn_mfma_f32_16x16x32_bf16(fa[m], fb[n], acc[m][n], 0, 0, 0);
    __syncthreads();
  }
  // epilogue: C/D layout col=lane&15, row=(lane>>4)*4+reg  [m89]
#pragma unroll
  for (int m = 0; m < 4; m++)
#pragma unroll
    for (int n = 0; n < 4; n++)
#pragma unroll
      for (int r = 0; r < 4; r++) {
        long row = m0 + wr * 64 + m * 16 + g * 4 + r;
        long col = n0 + wc * 64 + n * 16 + lr;
        float v = acc[m][n][r];
        if constexpr (EPI == 0) {
          long bb = row >> 8, t = row & 255, hh = col >> 6, e = col & 63;
          outU[(((bb * 16 + hh) * 256 + t) << 6) + e] = f2bf(v);
        } else if constexpr (EPI == 1) {
          long bb = row >> 8, t = row & 255, hh = col >> 6, e = col & 63;
          outU[(((bb * 16 + hh) * 64 + e) << 8) + t] = f2bf(v);
        } else if constexpr (EPI == 2) {
          long i = row * N + col;
          outF[i] = v + bias[col] + res[i];
        } else {
          outU[row * N + col] = f2bf(fmaxf(v + bias[col], 0.0f));
        }
      }
}

// ---------------- flash attention: 1 wave per (64 q rows, b, h) ------------
// q,k: [b,h,t,e] bf16; vt: [b,h,e,t] bf16; out: [b,t,h*64+e] bf16
__global__ __launch_bounds__(64) void attn_k(const ushort_t* __restrict__ q,
                                             const ushort_t* __restrict__ k,
                                             const ushort_t* __restrict__ vt,
                                             ushort_t* __restrict__ ao) {
  __shared__ __align__(16) ushort_t Ps[64][40];
  const int lane = threadIdx.x;
  const int g = lane >> 4, lr = lane & 15;
  const int blk = blockIdx.x;
  const int q4 = blk & 3;          // which 64-row q block
  const int bh = blk >> 2;
  const int bb = bh >> 4, hh = bh & 15;
  const int q0 = q4 * 64;
  const ushort_t* qb = q + (long)bh * 256 * 64;
  const ushort_t* kb = k + (long)bh * 256 * 64;
  const ushort_t* vb = vt + (long)bh * 64 * 256;
  // hoist Q fragments (A-layout: row=lane&15, k=8*(lane>>4)+j)
  bf16x8 qf[4][2];
#pragma unroll
  for (int m = 0; m < 4; m++)
#pragma unroll
    for (int ks = 0; ks < 2; ks++)
      qf[m][ks] = *(const bf16x8*)(qb + (q0 + m * 16 + lr) * 64 + ks * 32 + g * 8);
  f32x4 o[4][4] = {};
  float mrow[4][4], lrow[4][4];
#pragma unroll
  for (int m = 0; m < 4; m++)
#pragma unroll
    for (int r = 0; r < 4; r++) { mrow[m][r] = -__builtin_inff(); lrow[m][r] = 0.0f; }
  const float scale = 0.03125f;  // 1024^-0.5
  const int nkb = q0 / 32 + 2;   // causal: only blocks with keys <= q0+63
  for (int kbk = 0; kbk < nkb; kbk++) {
    // S = Q K^T  (16x16x32 over e=64 -> 2 k-steps)
    f32x4 s[4][2] = {};
#pragma unroll
    for (int ks = 0; ks < 2; ks++) {
      bf16x8 kf[2];
#pragma unroll
      for (int n = 0; n < 2; n++)
        kf[n] = *(const bf16x8*)(kb + (kbk * 32 + n * 16 + lr) * 64 + ks * 32 + g * 8);
#pragma unroll
      for (int m = 0; m < 4; m++)
#pragma unroll
        for (int n = 0; n < 2; n++)
          s[m][n] = __builtin_amdgcn_mfma_f32_16x16x32_bf16(qf[m][ks], kf[n], s[m][n], 0, 0, 0);
    }
    // scale + causal mask
#pragma unroll
    for (int m = 0; m < 4; m++)
#pragma unroll
      for (int n = 0; n < 2; n++)
#pragma unroll
        for (int r = 0; r < 4; r++) {
          int row = q0 + m * 16 + g * 4 + r;
          int col = kbk * 32 + n * 16 + lr;
          float v = s[m][n][r] * scale;
          s[m][n][r] = (col <= row) ? v : -1e30f;
        }
    // online softmax (rows live in 16-lane groups -> shfl_xor reduce)
#pragma unroll
    for (int m = 0; m < 4; m++)
#pragma unroll
      for (int r = 0; r < 4; r++) {
        float mx = fmaxf(s[m][0][r], s[m][1][r]);
#pragma unroll
        for (int off = 8; off; off >>= 1) mx = fmaxf(mx, __shfl_xor(mx, off));
        float mn = fmaxf(mrow[m][r], mx);
        float alpha = __expf(mrow[m][r] - mn);
        mrow[m][r] = mn;
        float rs = 0.0f;
#pragma unroll
        for (int n = 0; n < 2; n++) {
          float p = __expf(s[m][n][r] - mn);
          s[m][n][r] = p;
          rs += p;
        }
#pragma unroll
        for (int off = 8; off; off >>= 1) rs += __shfl_xor(rs, off);
        lrow[m][r] = lrow[m][r] * alpha + rs;
#pragma unroll
        for (int n = 0; n < 4; n++) o[m][n][r] *= alpha;
      }
    // P -> LDS (bf16) to reach MFMA A-layout
#pragma unroll
    for (int m = 0; m < 4; m++)
#pragma unroll
      for (int n = 0; n < 2; n++)
#pragma unroll
        for (int r = 0; r < 4; r++)
          Ps[m * 16 + g * 4 + r][n * 16 + lr] = f2bf(s[m][n][r]);
    __syncthreads();
    // O += P V   (A=P 64x32, B from vt rows = e)
    bf16x8 vf[4];
#pragma unroll
    for (int n = 0; n < 4; n++)
      vf[n] = *(const bf16x8*)(vb + (n * 16 + lr) * 256 + kbk * 32 + g * 8);
#pragma unroll
    for (int m = 0; m < 4; m++) {
      bf16x8 pa = *(const bf16x8*)&Ps[m * 16 + lr][g * 8];
#pragma unroll
      for (int n = 0; n < 4; n++)
        o[m][n] = __builtin_amdgcn_mfma_f32_16x16x32_bf16(pa, vf[n], o[m][n], 0, 0, 0);
    }
    __syncthreads();
  }
  // finalize + store [b,t,h*64+e]
#pragma unroll
  for (int m = 0; m < 4; m++)
#pragma unroll
    for (int r = 0; r < 4; r++) {
      float inv = 1.0f / lrow[m][r];
      long t = q0 + m * 16 + g * 4 + r;
#pragma unroll
      for (int n = 0; n < 4; n++) {
        long e = n * 16 + lr;
        ao[((long)bb * 256 + t) * 1024 + hh * 64 + e] = f2bf(o[m][n][r] * inv);
      }
    }
}

// ---------------- launch ---------------------------------------------------
// Workspace map (MB offsets, total 184 MB):
//   wqt@0 wkt@2 wvt@4 wpt@6 w1t@8 w2t@16  (bf16 N-major weights, 24 MB)
//   hb @24  (bf16 h, later h2; 32 MB)
//   X  @56  (128 MB): qbf@56 kbf@88 vtb@120 atb@152; ff1 aliases X@56 (128 MB)
// fp32 residual stream (h -> y -> h2 -> out) lives IN d_out (in-place LN +
// read-then-write epilogues; every replay fully rewrites it).
extern "C" void kernel_launch(void* const* d_in, const int* in_sizes, int n_in,
                              void* d_out, int out_size, void* d_ws, size_t ws_size,
                              hipStream_t stream) {
  const float* x     = (const float*)d_in[0];
  const float* ln1g  = (const float*)d_in[1];
  const float* ln1b  = (const float*)d_in[2];
  const float* Wq    = (const float*)d_in[3];
  const float* Wk    = (const float*)d_in[4];
  const float* Wv    = (const float*)d_in[5];
  const float* Wproj = (const float*)d_in[6];
  const float* bproj = (const float*)d_in[7];
  const float* ln2g  = (const float*)d_in[8];
  const float* ln2b  = (const float*)d_in[9];
  const float* W1    = (const float*)d_in[10];
  const float* b1    = (const float*)d_in[11];
  const float* W2    = (const float*)d_in[12];
  const float* b2    = (const float*)d_in[13];

  const long NEED = 184L << 20;
  if (ws_size < (size_t)NEED) {
    // diagnostic: report ws_size (in MB) through the absmax check
    fill_k<<<(out_size + 255) / 256, 256, 0, stream>>>((float*)d_out, out_size,
                                                       (float)(ws_size >> 20));
    return;
  }

  char* ws = (char*)d_ws;
  const long MB = 1 << 20;
  ushort_t* wqt = (ushort_t*)(ws + 0 * MB);
  ushort_t* wkt = (ushort_t*)(ws + 2 * MB);
  ushort_t* wvt = (ushort_t*)(ws + 4 * MB);
  ushort_t* wpt = (ushort_t*)(ws + 6 * MB);
  ushort_t* w1t = (ushort_t*)(ws + 8 * MB);
  ushort_t* w2t = (ushort_t*)(ws + 16 * MB);
  ushort_t* hb  = (ushort_t*)(ws + 24 * MB);
  ushort_t* qbf = (ushort_t*)(ws + 56 * MB);
  ushort_t* kbf = (ushort_t*)(ws + 88 * MB);
  ushort_t* vtb = (ushort_t*)(ws + 120 * MB);
  ushort_t* atb = (ushort_t*)(ws + 152 * MB);
  ushort_t* ff1 = (ushort_t*)(ws + 56 * MB);  // aliases q/k/vt/attn (dead by then)
  float*    yf  = (float*)d_out;              // h -> y -> h2 -> out

  // weights -> bf16, B^T (NxK) layout
  transpose_w<<<dim3(32, 2, 16), 256, 0, stream>>>(Wq, wqt, 1024, 64);
  transpose_w<<<dim3(32, 2, 16), 256, 0, stream>>>(Wk, wkt, 1024, 64);
  transpose_w<<<dim3(32, 2, 16), 256, 0, stream>>>(Wv, wvt, 1024, 64);
  transpose_w<<<dim3(32, 32, 1), 256, 0, stream>>>(Wproj, wpt, 1024, 1024);
  transpose_w<<<dim3(32, 128, 1), 256, 0, stream>>>(W1, w1t, 1024, 4096);
  transpose_w<<<dim3(128, 32, 1), 256, 0, stream>>>(W2, w2t, 4096, 1024);

  // h = LN1(x): fp32 into d_out, bf16 into hb
  ln_k<<<16384, 256, 0, stream>>>(x, ln1g, ln1b, yf, hb);
  // q/k/v projections
  gemm_bf16<0><<<dim3(128, 8), 256, 0, stream>>>(hb, wqt, 16384, 1024, 1024, nullptr, nullptr, nullptr, qbf);
  gemm_bf16<0><<<dim3(128, 8), 256, 0, stream>>>(hb, wkt, 16384, 1024, 1024, nullptr, nullptr, nullptr, kbf);
  gemm_bf16<1><<<dim3(128, 8), 256, 0, stream>>>(hb, wvt, 16384, 1024, 1024, nullptr, nullptr, nullptr, vtb);
  // attention
  attn_k<<<4096, 64, 0, stream>>>(qbf, kbf, vtb, atb);
  // y = h + attn @ Wproj + bproj   (in-place over d_out)
  gemm_bf16<2><<<dim3(128, 8), 256, 0, stream>>>(atb, wpt, 16384, 1024, 1024, bproj, yf, yf, nullptr);
  // h2 = LN2(y): fp32 in-place over d_out, bf16 into hb
  ln_k<<<16384, 256, 0, stream>>>(yf, ln2g, ln2b, yf, hb);
  // ff1 = relu(h2 @ W1 + b1)
  gemm_bf16<3><<<dim3(128, 32), 256, 0, stream>>>(hb, w1t, 16384, 4096, 1024, b1, nullptr, nullptr, ff1);
  // out = h2 + ff1 @ W2 + b2   (in-place over d_out)
  gemm_bf16<2><<<dim3(128, 8), 256, 0, stream>>>(ff1, w2t, 16384, 1024, 4096, b2, yf, yf, nullptr);
}

// Round 3
// 877.524 us; speedup vs baseline: 1.0589x; 1.0589x over previous
//
#include <hip/hip_runtime.h>

typedef __bf16 bf16x8 __attribute__((ext_vector_type(8)));
typedef float f32x4 __attribute__((ext_vector_type(4)));
typedef unsigned short ushort_t;

__device__ __forceinline__ ushort_t f2bf(float f) {
  unsigned int u = __float_as_uint(f);
  u += 0x7fffu + ((u >> 16) & 1u);
  return (ushort_t)(u >> 16);
}

// async global->LDS, 16 bytes per lane (dest = wave-uniform base + lane*16)
__device__ __forceinline__ void gl_lds16(const ushort_t* g, ushort_t* l) {
  __builtin_amdgcn_global_load_lds(
      (const __attribute__((address_space(1))) void*)g,
      (__attribute__((address_space(3))) void*)l, 16, 0, 0);
}

__global__ __launch_bounds__(256) void fill_k(float* __restrict__ p, long n, float v) {
  long i = (long)blockIdx.x * 256 + threadIdx.x;
  if (i < n) p[i] = v;
}

// ---------------- batched transpose: fp32 Z x R x C  ->  bf16 Z x C x R ----
__global__ __launch_bounds__(256) void transpose_w(const float* __restrict__ in,
                                                   ushort_t* __restrict__ out,
                                                   int R, int C) {
  __shared__ float tile[32][33];
  const float* inb = in + (long)blockIdx.z * R * C;
  ushort_t* outb = out + (long)blockIdx.z * R * C;
  int r0 = blockIdx.x * 32, c0 = blockIdx.y * 32;
  int tx = threadIdx.x & 31, ty = threadIdx.x >> 5;
#pragma unroll
  for (int i = ty; i < 32; i += 8) tile[i][tx] = inb[(long)(r0 + i) * C + (c0 + tx)];
  __syncthreads();
#pragma unroll
  for (int i = ty; i < 32; i += 8) outb[(long)(c0 + i) * R + (r0 + tx)] = f2bf(tile[tx][i]);
}

// ---------------- layernorm: one row (D=1024) per 256-thread block ---------
// In-place safe (outF may alias x): each thread reads its 4 elems before any write.
__global__ __launch_bounds__(256) void ln_k(const float* __restrict__ x,
                                            const float* __restrict__ g,
                                            const float* __restrict__ b,
                                            float* __restrict__ outF,
                                            ushort_t* __restrict__ outU) {
  __shared__ float red[8];
  long row = blockIdx.x;
  int tid = threadIdx.x;
  float4 v = ((const float4*)(x + row * 1024))[tid];
  float s = v.x + v.y + v.z + v.w;
#pragma unroll
  for (int off = 32; off; off >>= 1) s += __shfl_xor(s, off);
  int w = tid >> 6;
  if ((tid & 63) == 0) red[w] = s;
  __syncthreads();
  float mean = (red[0] + red[1] + red[2] + red[3]) * (1.0f / 1024.0f);
  float dx = v.x - mean, dy = v.y - mean, dz = v.z - mean, dw = v.w - mean;
  float s2 = dx * dx + dy * dy + dz * dz + dw * dw;
#pragma unroll
  for (int off = 32; off; off >>= 1) s2 += __shfl_xor(s2, off);
  if ((tid & 63) == 0) red[4 + w] = s2;
  __syncthreads();
  float var = (red[4] + red[5] + red[6] + red[7]) * (1.0f / 1024.0f);
  float rstd = rsqrtf(var + 1e-5f);
  int c = tid * 4;
  float o0 = dx * rstd * g[c + 0] + b[c + 0];
  float o1 = dy * rstd * g[c + 1] + b[c + 1];
  float o2 = dz * rstd * g[c + 2] + b[c + 2];
  float o3 = dw * rstd * g[c + 3] + b[c + 3];
  ((float4*)(outF + row * 1024))[tid] = make_float4(o0, o1, o2, o3);
  ushort4 u;
  u.x = f2bf(o0); u.y = f2bf(o1); u.z = f2bf(o2); u.w = f2bf(o3);
  ((ushort4*)(outU + row * 1024))[tid] = u;
}

// ---------------- bf16 GEMM: C(MxN) = A(MxK) * Bt(NxK)^T, fp32 accum -------
// m97 structure: 128x128 tile, BK=32, 256 threads = 4 waves (2x2), LINEAR
// [128][32] LDS tiles staged via global_load_lds width=16 (4 issues/K-step).
// Epilogues:
//  EPI 0: bf16 out in [b,h,t,e] layout (Q/K)
//  EPI 1: bf16 out in [b,h,e,t] layout (V transposed)
//  EPI 2: fp32 out = acc + bias[col] + res[row*N+col]   (proj->y, ff2->out)
//  EPI 3: bf16 out = relu(acc + bias[col])              (ff1)
template <int EPI>
__global__ __launch_bounds__(256) void gemm_bf16(const ushort_t* __restrict__ A,
                                                 const ushort_t* __restrict__ Bt,
                                                 int M, int N, int K,
                                                 const float* __restrict__ bias,
                                                 const float* res, float* outF,
                                                 ushort_t* __restrict__ outU) {
  __shared__ __align__(16) ushort_t As[128 * 32];
  __shared__ __align__(16) ushort_t Bs[128 * 32];
  const int tid = threadIdx.x;
  const int lane = tid & 63;
  const int w = tid >> 6;
  const int wr = w >> 1, wc = w & 1;
  const int g = lane >> 4, lr = lane & 15;
  const long m0 = (long)blockIdx.x * 128;
  const long n0 = (long)blockIdx.y * 128;
  // staging geometry: wave w covers rows [w*32, w*32+32); issue i adds 16 rows.
  const int srow = w * 32 + (lane >> 2);   // issue-0 row
  const int scol = (lane & 3) * 8;         // k offset in elements (16B granules)
  const ushort_t* Ag0 = A + (long)(m0 + srow) * K + scol;
  const ushort_t* Ag1 = Ag0 + 16L * K;
  const ushort_t* Bg0 = Bt + (long)(n0 + srow) * K + scol;
  const ushort_t* Bg1 = Bg0 + 16L * K;
  ushort_t* Al0 = As + w * 1024 + lane * 8;
  ushort_t* Al1 = Al0 + 512;
  ushort_t* Bl0 = Bs + w * 1024 + lane * 8;
  ushort_t* Bl1 = Bl0 + 512;
  f32x4 acc[4][4] = {};
  for (int k0 = 0; k0 < K; k0 += 32) {
    gl_lds16(Ag0 + k0, Al0);
    gl_lds16(Ag1 + k0, Al1);
    gl_lds16(Bg0 + k0, Bl0);
    gl_lds16(Bg1 + k0, Bl1);
    __syncthreads();   // compiler drains vmcnt before barrier -> tiles ready
    bf16x8 fa[4], fb[4];
#pragma unroll
    for (int m = 0; m < 4; m++)
      fa[m] = *(const bf16x8*)(As + (wr * 64 + m * 16 + lr) * 32 + g * 8);
#pragma unroll
    for (int n = 0; n < 4; n++)
      fb[n] = *(const bf16x8*)(Bs + (wc * 64 + n * 16 + lr) * 32 + g * 8);
#pragma unroll
    for (int m = 0; m < 4; m++)
#pragma unroll
      for (int n = 0; n < 4; n++)
        acc[m][n] = __builtin_amdgcn_mfma_f32_16x16x32_bf16(fa[m], fb[n], acc[m][n], 0, 0, 0);
    __syncthreads();   // protect LDS before next stage overwrites
  }
  // epilogue: C/D layout col=lane&15, row=(lane>>4)*4+reg  [m89]
#pragma unroll
  for (int m = 0; m < 4; m++)
#pragma unroll
    for (int n = 0; n < 4; n++)
#pragma unroll
      for (int r = 0; r < 4; r++) {
        long row = m0 + wr * 64 + m * 16 + g * 4 + r;
        long col = n0 + wc * 64 + n * 16 + lr;
        float v = acc[m][n][r];
        if constexpr (EPI == 0) {
          long bb = row >> 8, t = row & 255, hh = col >> 6, e = col & 63;
          outU[(((bb * 16 + hh) * 256 + t) << 6) + e] = f2bf(v);
        } else if constexpr (EPI == 1) {
          long bb = row >> 8, t = row & 255, hh = col >> 6, e = col & 63;
          outU[(((bb * 16 + hh) * 64 + e) << 8) + t] = f2bf(v);
        } else if constexpr (EPI == 2) {
          long i = row * N + col;
          outF[i] = v + bias[col] + res[i];
        } else {
          outU[row * N + col] = f2bf(fmaxf(v + bias[col], 0.0f));
        }
      }
}

// ---------------- flash attention: 1 wave per (64 q rows, b, h) ------------
// q,k: [b,h,t,e] bf16; vt: [b,h,e,t] bf16; out: [b,t,h*64+e] bf16
__global__ __launch_bounds__(64) void attn_k(const ushort_t* __restrict__ q,
                                             const ushort_t* __restrict__ k,
                                             const ushort_t* __restrict__ vt,
                                             ushort_t* __restrict__ ao) {
  __shared__ __align__(16) ushort_t Ps[64][40];
  const int lane = threadIdx.x;
  const int g = lane >> 4, lr = lane & 15;
  const int blk = blockIdx.x;
  const int q4 = blk & 3;          // which 64-row q block
  const int bh = blk >> 2;
  const int bb = bh >> 4, hh = bh & 15;
  const int q0 = q4 * 64;
  const ushort_t* qb = q + (long)bh * 256 * 64;
  const ushort_t* kb = k + (long)bh * 256 * 64;
  const ushort_t* vb = vt + (long)bh * 64 * 256;
  // hoist Q fragments (A-layout: row=lane&15, k=8*(lane>>4)+j)
  bf16x8 qf[4][2];
#pragma unroll
  for (int m = 0; m < 4; m++)
#pragma unroll
    for (int ks = 0; ks < 2; ks++)
      qf[m][ks] = *(const bf16x8*)(qb + (q0 + m * 16 + lr) * 64 + ks * 32 + g * 8);
  f32x4 o[4][4] = {};
  float mrow[4][4], lrow[4][4];
#pragma unroll
  for (int m = 0; m < 4; m++)
#pragma unroll
    for (int r = 0; r < 4; r++) { mrow[m][r] = -__builtin_inff(); lrow[m][r] = 0.0f; }
  const float scale = 0.03125f;  // 1024^-0.5
  const int nkb = q0 / 32 + 2;   // causal: only blocks with keys <= q0+63
  for (int kbk = 0; kbk < nkb; kbk++) {
    // S = Q K^T  (16x16x32 over e=64 -> 2 k-steps)
    f32x4 s[4][2] = {};
#pragma unroll
    for (int ks = 0; ks < 2; ks++) {
      bf16x8 kf[2];
#pragma unroll
      for (int n = 0; n < 2; n++)
        kf[n] = *(const bf16x8*)(kb + (kbk * 32 + n * 16 + lr) * 64 + ks * 32 + g * 8);
#pragma unroll
      for (int m = 0; m < 4; m++)
#pragma unroll
        for (int n = 0; n < 2; n++)
          s[m][n] = __builtin_amdgcn_mfma_f32_16x16x32_bf16(qf[m][ks], kf[n], s[m][n], 0, 0, 0);
    }
    // scale + causal mask
#pragma unroll
    for (int m = 0; m < 4; m++)
#pragma unroll
      for (int n = 0; n < 2; n++)
#pragma unroll
        for (int r = 0; r < 4; r++) {
          int row = q0 + m * 16 + g * 4 + r;
          int col = kbk * 32 + n * 16 + lr;
          float v = s[m][n][r] * scale;
          s[m][n][r] = (col <= row) ? v : -1e30f;
        }
    // online softmax (rows live in 16-lane groups -> shfl_xor reduce)
#pragma unroll
    for (int m = 0; m < 4; m++)
#pragma unroll
      for (int r = 0; r < 4; r++) {
        float mx = fmaxf(s[m][0][r], s[m][1][r]);
#pragma unroll
        for (int off = 8; off; off >>= 1) mx = fmaxf(mx, __shfl_xor(mx, off));
        float mn = fmaxf(mrow[m][r], mx);
        float alpha = __expf(mrow[m][r] - mn);
        mrow[m][r] = mn;
        float rs = 0.0f;
#pragma unroll
        for (int n = 0; n < 2; n++) {
          float p = __expf(s[m][n][r] - mn);
          s[m][n][r] = p;
          rs += p;
        }
#pragma unroll
        for (int off = 8; off; off >>= 1) rs += __shfl_xor(rs, off);
        lrow[m][r] = lrow[m][r] * alpha + rs;
#pragma unroll
        for (int n = 0; n < 4; n++) o[m][n][r] *= alpha;
      }
    // P -> LDS (bf16) to reach MFMA A-layout
#pragma unroll
    for (int m = 0; m < 4; m++)
#pragma unroll
      for (int n = 0; n < 2; n++)
#pragma unroll
        for (int r = 0; r < 4; r++)
          Ps[m * 16 + g * 4 + r][n * 16 + lr] = f2bf(s[m][n][r]);
    __syncthreads();
    // O += P V   (A=P 64x32, B from vt rows = e)
    bf16x8 vf[4];
#pragma unroll
    for (int n = 0; n < 4; n++)
      vf[n] = *(const bf16x8*)(vb + (n * 16 + lr) * 256 + kbk * 32 + g * 8);
#pragma unroll
    for (int m = 0; m < 4; m++) {
      bf16x8 pa = *(const bf16x8*)&Ps[m * 16 + lr][g * 8];
#pragma unroll
      for (int n = 0; n < 4; n++)
        o[m][n] = __builtin_amdgcn_mfma_f32_16x16x32_bf16(pa, vf[n], o[m][n], 0, 0, 0);
    }
    __syncthreads();
  }
  // finalize + store [b,t,h*64+e]
#pragma unroll
  for (int m = 0; m < 4; m++)
#pragma unroll
    for (int r = 0; r < 4; r++) {
      float inv = 1.0f / lrow[m][r];
      long t = q0 + m * 16 + g * 4 + r;
#pragma unroll
      for (int n = 0; n < 4; n++) {
        long e = n * 16 + lr;
        ao[((long)bb * 256 + t) * 1024 + hh * 64 + e] = f2bf(o[m][n][r] * inv);
      }
    }
}

// ---------------- launch ---------------------------------------------------
// Workspace map (MB offsets, total 184 MB):
//   wqt@0 wkt@2 wvt@4 wpt@6 w1t@8 w2t@16  (bf16 N-major weights, 24 MB)
//   hb @24  (bf16 h, later h2; 32 MB)
//   X  @56  (128 MB): qbf@56 kbf@88 vtb@120 atb@152; ff1 aliases X@56 (128 MB)
// fp32 residual stream (h -> y -> h2 -> out) lives IN d_out (in-place LN +
// read-then-write epilogues; every replay fully rewrites it).
extern "C" void kernel_launch(void* const* d_in, const int* in_sizes, int n_in,
                              void* d_out, int out_size, void* d_ws, size_t ws_size,
                              hipStream_t stream) {
  const float* x     = (const float*)d_in[0];
  const float* ln1g  = (const float*)d_in[1];
  const float* ln1b  = (const float*)d_in[2];
  const float* Wq    = (const float*)d_in[3];
  const float* Wk    = (const float*)d_in[4];
  const float* Wv    = (const float*)d_in[5];
  const float* Wproj = (const float*)d_in[6];
  const float* bproj = (const float*)d_in[7];
  const float* ln2g  = (const float*)d_in[8];
  const float* ln2b  = (const float*)d_in[9];
  const float* W1    = (const float*)d_in[10];
  const float* b1    = (const float*)d_in[11];
  const float* W2    = (const float*)d_in[12];
  const float* b2    = (const float*)d_in[13];

  const long NEED = 184L << 20;
  if (ws_size < (size_t)NEED) {
    fill_k<<<(out_size + 255) / 256, 256, 0, stream>>>((float*)d_out, out_size,
                                                       (float)(ws_size >> 20));
    return;
  }

  char* ws = (char*)d_ws;
  const long MB = 1 << 20;
  ushort_t* wqt = (ushort_t*)(ws + 0 * MB);
  ushort_t* wkt = (ushort_t*)(ws + 2 * MB);
  ushort_t* wvt = (ushort_t*)(ws + 4 * MB);
  ushort_t* wpt = (ushort_t*)(ws + 6 * MB);
  ushort_t* w1t = (ushort_t*)(ws + 8 * MB);
  ushort_t* w2t = (ushort_t*)(ws + 16 * MB);
  ushort_t* hb  = (ushort_t*)(ws + 24 * MB);
  ushort_t* qbf = (ushort_t*)(ws + 56 * MB);
  ushort_t* kbf = (ushort_t*)(ws + 88 * MB);
  ushort_t* vtb = (ushort_t*)(ws + 120 * MB);
  ushort_t* atb = (ushort_t*)(ws + 152 * MB);
  ushort_t* ff1 = (ushort_t*)(ws + 56 * MB);  // aliases q/k/vt/attn (dead by then)
  float*    yf  = (float*)d_out;              // h -> y -> h2 -> out

  // weights -> bf16, B^T (NxK) layout
  transpose_w<<<dim3(32, 2, 16), 256, 0, stream>>>(Wq, wqt, 1024, 64);
  transpose_w<<<dim3(32, 2, 16), 256, 0, stream>>>(Wk, wkt, 1024, 64);
  transpose_w<<<dim3(32, 2, 16), 256, 0, stream>>>(Wv, wvt, 1024, 64);
  transpose_w<<<dim3(32, 32, 1), 256, 0, stream>>>(Wproj, wpt, 1024, 1024);
  transpose_w<<<dim3(32, 128, 1), 256, 0, stream>>>(W1, w1t, 1024, 4096);
  transpose_w<<<dim3(128, 32, 1), 256, 0, stream>>>(W2, w2t, 4096, 1024);

  // h = LN1(x): fp32 into d_out, bf16 into hb
  ln_k<<<16384, 256, 0, stream>>>(x, ln1g, ln1b, yf, hb);
  // q/k/v projections
  gemm_bf16<0><<<dim3(128, 8), 256, 0, stream>>>(hb, wqt, 16384, 1024, 1024, nullptr, nullptr, nullptr, qbf);
  gemm_bf16<0><<<dim3(128, 8), 256, 0, stream>>>(hb, wkt, 16384, 1024, 1024, nullptr, nullptr, nullptr, kbf);
  gemm_bf16<1><<<dim3(128, 8), 256, 0, stream>>>(hb, wvt, 16384, 1024, 1024, nullptr, nullptr, nullptr, vtb);
  // attention
  attn_k<<<4096, 64, 0, stream>>>(qbf, kbf, vtb, atb);
  // y = h + attn @ Wproj + bproj   (in-place over d_out)
  gemm_bf16<2><<<dim3(128, 8), 256, 0, stream>>>(atb, wpt, 16384, 1024, 1024, bproj, yf, yf, nullptr);
  // h2 = LN2(y): fp32 in-place over d_out, bf16 into hb
  ln_k<<<16384, 256, 0, stream>>>(yf, ln2g, ln2b, yf, hb);
  // ff1 = relu(h2 @ W1 + b1)
  gemm_bf16<3><<<dim3(128, 32), 256, 0, stream>>>(hb, w1t, 16384, 4096, 1024, b1, nullptr, nullptr, ff1);
  // out = h2 + ff1 @ W2 + b2   (in-place over d_out)
  gemm_bf16<2><<<dim3(128, 8), 256, 0, stream>>>(ff1, w2t, 16384, 1024, 4096, b2, yf, yf, nullptr);
}

// Round 4
// 676.160 us; speedup vs baseline: 1.3742x; 1.2978x over previous
//
#include <hip/hip_runtime.h>

typedef __bf16 bf16x8 __attribute__((ext_vector_type(8)));
typedef float f32x4 __attribute__((ext_vector_type(4)));
typedef unsigned short ushort_t;

__device__ __forceinline__ ushort_t f2bf(float f) {
  unsigned int u = __float_as_uint(f);
  u += 0x7fffu + ((u >> 16) & 1u);
  return (ushort_t)(u >> 16);
}

// async global->LDS, 16 bytes per lane (dest = wave-uniform base + lane*16)
__device__ __forceinline__ void gl_lds16(const ushort_t* g, const char* l) {
  __builtin_amdgcn_global_load_lds(
      (const __attribute__((address_space(1))) void*)g,
      (__attribute__((address_space(3))) void*)l, 16, 0, 0);
}

__global__ __launch_bounds__(256) void fill_k(float* __restrict__ p, long n, float v) {
  long i = (long)blockIdx.x * 256 + threadIdx.x;
  if (i < n) p[i] = v;
}

// ---------------- batched transpose: fp32 Z x R x C  ->  bf16 Z x C x R ----
__global__ __launch_bounds__(256) void transpose_w(const float* __restrict__ in,
                                                   ushort_t* __restrict__ out,
                                                   int R, int C) {
  __shared__ float tile[32][33];
  const float* inb = in + (long)blockIdx.z * R * C;
  ushort_t* outb = out + (long)blockIdx.z * R * C;
  int r0 = blockIdx.x * 32, c0 = blockIdx.y * 32;
  int tx = threadIdx.x & 31, ty = threadIdx.x >> 5;
#pragma unroll
  for (int i = ty; i < 32; i += 8) tile[i][tx] = inb[(long)(r0 + i) * C + (c0 + tx)];
  __syncthreads();
#pragma unroll
  for (int i = ty; i < 32; i += 8) outb[(long)(c0 + i) * R + (r0 + tx)] = f2bf(tile[tx][i]);
}

// ---------------- layernorm: one row (D=1024) per 256-thread block ---------
__global__ __launch_bounds__(256) void ln_k(const float* __restrict__ x,
                                            const float* __restrict__ g,
                                            const float* __restrict__ b,
                                            float* __restrict__ outF,
                                            ushort_t* __restrict__ outU) {
  __shared__ float red[8];
  long row = blockIdx.x;
  int tid = threadIdx.x;
  float4 v = ((const float4*)(x + row * 1024))[tid];
  float s = v.x + v.y + v.z + v.w;
#pragma unroll
  for (int off = 32; off; off >>= 1) s += __shfl_xor(s, off);
  int w = tid >> 6;
  if ((tid & 63) == 0) red[w] = s;
  __syncthreads();
  float mean = (red[0] + red[1] + red[2] + red[3]) * (1.0f / 1024.0f);
  float dx = v.x - mean, dy = v.y - mean, dz = v.z - mean, dw = v.w - mean;
  float s2 = dx * dx + dy * dy + dz * dz + dw * dw;
#pragma unroll
  for (int off = 32; off; off >>= 1) s2 += __shfl_xor(s2, off);
  if ((tid & 63) == 0) red[4 + w] = s2;
  __syncthreads();
  float var = (red[4] + red[5] + red[6] + red[7]) * (1.0f / 1024.0f);
  float rstd = rsqrtf(var + 1e-5f);
  int c = tid * 4;
  float o0 = dx * rstd * g[c + 0] + b[c + 0];
  float o1 = dy * rstd * g[c + 1] + b[c + 1];
  float o2 = dz * rstd * g[c + 2] + b[c + 2];
  float o3 = dw * rstd * g[c + 3] + b[c + 3];
  ((float4*)(outF + row * 1024))[tid] = make_float4(o0, o1, o2, o3);
  ushort4 u;
  u.x = f2bf(o0); u.y = f2bf(o1); u.z = f2bf(o2); u.w = f2bf(o3);
  ((ushort4*)(outU + row * 1024))[tid] = u;
}

// ---------------- 256x256 8-wave phase-interleaved bf16 GEMM ---------------
// C(MxN) = A(MxK) * Bt(NxK)^T, fp32 accum. BK=32, 3 LDS buffers (A,B each
// 16KB/tile), prefetch 2 K-tiles ahead, counted vmcnt(4) at tile boundary
// (T4), 2 phases/K-tile each {ds_read | 2x global_load_lds | barrier |
// lgkmcnt(0) | setprio(1) 16 MFMA setprio(0) | barrier} (T3+T5).
// T2 swizzle: 16B slot s8 = ((r&1)*4+g) ^ (r>>1 & 7); LDS byte(r,g) =
// (r>>1)*128 + s8*16. gl_lds dest linear; global source inverse-permuted.
// Epilogues: 0: bf16 [b,h,t,e] (Q/K)  1: bf16 [b,h,e,t] (V^T)
//            2: fp32 acc+bias[col]+res[i]  3: bf16 relu(acc+bias[col])
template <int EPI>
__global__ __launch_bounds__(512, 2) void gemm256(const ushort_t* __restrict__ A,
                                                  const ushort_t* __restrict__ Bt,
                                                  int M, int N, int K, int NBC,
                                                  const float* __restrict__ bias,
                                                  const float* res, float* outF,
                                                  ushort_t* __restrict__ outU) {
  __shared__ __align__(16) char lds[98304];  // A: [0,49152) B: [49152,98304)
  const int tid = threadIdx.x;
  const int lane = tid & 63;
  const int w = tid >> 6;            // 0..7
  const int wr = w >> 2, wc = w & 3; // 2 x 4 wave grid
  const int g = lane >> 4, lr = lane & 15;
  // T1: bijective XCD swizzle (gridDim.x % 8 == 0), row-major tile order
  const int cpx = gridDim.x >> 3;
  const int wg = (blockIdx.x & 7) * cpx + (blockIdx.x >> 3);
  const long m0 = (long)(wg / NBC) * 256;
  const long n0 = (long)(wg % NBC) * 256;
  // staging source geometry (inverse of the read swizzle)
  const int u = (tid & 7) ^ ((tid >> 3) & 7);
  const int rbase = ((tid >> 3) << 1) | (u >> 2);
  const int gcol = (u & 3) * 8;
  const ushort_t* sA0 = A + (m0 + rbase) * (long)K + gcol;
  const ushort_t* sA1 = A + (m0 + 128 + rbase) * (long)K + gcol;
  const ushort_t* sB0 = Bt + (n0 + rbase) * (long)K + gcol;
  const ushort_t* sB1 = Bt + (n0 + 128 + rbase) * (long)K + gcol;
  // LDS read bases (bytes); frag f adds f*1024
  const int swz = (((lr & 1) << 2) + g) ^ (lr >> 1);
  const int aRd = wr * 8192 + (lr >> 1) * 128 + swz * 16;
  const int bRd = 49152 + wc * 4096 + (lr >> 1) * 128 + swz * 16;
  const int dA = tid * 16;           // staging dest within A region (+wo +j*8192)
  const int dB = 49152 + tid * 16;
  const int NT = K >> 5;

  f32x4 acc[8][4] = {};

  // prologue: stage tiles 0 -> buf0, 1 -> buf1 (issue order = age order)
  gl_lds16(sA0, lds + 0 + dA);
  gl_lds16(sA1, lds + 8192 + dA);
  gl_lds16(sB0, lds + 0 + dB);
  gl_lds16(sB1, lds + 8192 + dB);
  gl_lds16(sA0 + 32, lds + 16384 + dA);
  gl_lds16(sA1 + 32, lds + 16384 + 8192 + dA);
  gl_lds16(sB0 + 32, lds + 16384 + dB);
  gl_lds16(sB1 + 32, lds + 16384 + 8192 + dB);
  asm volatile("s_waitcnt vmcnt(4)" ::: "memory");  // tile0 landed
  __builtin_amdgcn_s_barrier();

  int ro = 0, wo = 32768;
  for (int t = 0; t < NT; ++t) {
    const bool st = (t + 2 < NT);
    const long ks = (long)(t + 2) * 32;
    bf16x8 fa[4], fb[4];
    // ---- phase 0: read A(mf0-3)+B(all), stage next A, MFMA upper half ----
#pragma unroll
    for (int mf = 0; mf < 4; ++mf)
      fa[mf] = *(const bf16x8*)(lds + ro + aRd + mf * 1024);
#pragma unroll
    for (int nf = 0; nf < 4; ++nf)
      fb[nf] = *(const bf16x8*)(lds + ro + bRd + nf * 1024);
    if (st) {
      gl_lds16(sA0 + ks, lds + wo + dA);
      gl_lds16(sA1 + ks, lds + wo + 8192 + dA);
    }
    __builtin_amdgcn_s_barrier();
    asm volatile("s_waitcnt lgkmcnt(0)" ::: "memory");
    __builtin_amdgcn_s_setprio(1);
#pragma unroll
    for (int mf = 0; mf < 4; ++mf)
#pragma unroll
      for (int nf = 0; nf < 4; ++nf)
        acc[mf][nf] = __builtin_amdgcn_mfma_f32_16x16x32_bf16(fa[mf], fb[nf], acc[mf][nf], 0, 0, 0);
    __builtin_amdgcn_s_setprio(0);
    __builtin_amdgcn_s_barrier();
    // ---- phase 1: read A(mf4-7), stage next B, MFMA lower half -----------
#pragma unroll
    for (int mf = 0; mf < 4; ++mf)
      fa[mf] = *(const bf16x8*)(lds + ro + aRd + (4 + mf) * 1024);
    if (st) {
      gl_lds16(sB0 + ks, lds + wo + dB);
      gl_lds16(sB1 + ks, lds + wo + 8192 + dB);
    }
    __builtin_amdgcn_s_barrier();
    asm volatile("s_waitcnt lgkmcnt(0)" ::: "memory");
    __builtin_amdgcn_s_setprio(1);
#pragma unroll
    for (int mf = 0; mf < 4; ++mf)
#pragma unroll
      for (int nf = 0; nf < 4; ++nf)
        acc[4 + mf][nf] = __builtin_amdgcn_mfma_f32_16x16x32_bf16(fa[mf], fb[nf], acc[4 + mf][nf], 0, 0, 0);
    __builtin_amdgcn_s_setprio(0);
    // tile boundary: counted wait (T4) — next tile's 4 issues must have
    // landed; the 4 just-issued (t+2) may stay in flight.
    if (st) asm volatile("s_waitcnt vmcnt(4)" ::: "memory");
    else    asm volatile("s_waitcnt vmcnt(0)" ::: "memory");
    __builtin_amdgcn_s_barrier();
    ro += 16384; if (ro == 49152) ro = 0;
    wo += 16384; if (wo == 49152) wo = 0;
  }

  // epilogue: C/D frag layout col=lr, row=g*4+r  [m89]
#pragma unroll
  for (int mf = 0; mf < 8; ++mf)
#pragma unroll
    for (int nf = 0; nf < 4; ++nf)
#pragma unroll
      for (int r = 0; r < 4; ++r) {
        long row = m0 + wr * 128 + mf * 16 + g * 4 + r;
        long col = n0 + wc * 64 + nf * 16 + lr;
        float v = acc[mf][nf][r];
        if constexpr (EPI == 0) {
          long bb = row >> 8, tt = row & 255, hh = col >> 6, e = col & 63;
          outU[(((bb * 16 + hh) * 256 + tt) << 6) + e] = f2bf(v);
        } else if constexpr (EPI == 1) {
          long bb = row >> 8, tt = row & 255, hh = col >> 6, e = col & 63;
          outU[(((bb * 16 + hh) * 64 + e) << 8) + tt] = f2bf(v);
        } else if constexpr (EPI == 2) {
          long i = row * N + col;
          outF[i] = v + bias[col] + res[i];
        } else {
          outU[row * N + col] = f2bf(fmaxf(v + bias[col], 0.0f));
        }
      }
}

// ---------------- flash attention: 1 wave per (64 q rows, b, h) ------------
// q,k: [b,h,t,e] bf16; vt: [b,h,e,t] bf16; out: [b,t,h*64+e] bf16
__global__ __launch_bounds__(64) void attn_k(const ushort_t* __restrict__ q,
                                             const ushort_t* __restrict__ k,
                                             const ushort_t* __restrict__ vt,
                                             ushort_t* __restrict__ ao) {
  __shared__ __align__(16) ushort_t Ps[64][40];
  const int lane = threadIdx.x;
  const int g = lane >> 4, lr = lane & 15;
  const int blk = blockIdx.x;
  const int q4 = blk & 3;
  const int bh = blk >> 2;
  const int bb = bh >> 4, hh = bh & 15;
  const int q0 = q4 * 64;
  const ushort_t* qb = q + (long)bh * 256 * 64;
  const ushort_t* kb = k + (long)bh * 256 * 64;
  const ushort_t* vb = vt + (long)bh * 64 * 256;
  bf16x8 qf[4][2];
#pragma unroll
  for (int m = 0; m < 4; m++)
#pragma unroll
    for (int ks = 0; ks < 2; ks++)
      qf[m][ks] = *(const bf16x8*)(qb + (q0 + m * 16 + lr) * 64 + ks * 32 + g * 8);
  f32x4 o[4][4] = {};
  float mrow[4][4], lrow[4][4];
#pragma unroll
  for (int m = 0; m < 4; m++)
#pragma unroll
    for (int r = 0; r < 4; r++) { mrow[m][r] = -__builtin_inff(); lrow[m][r] = 0.0f; }
  const float scale = 0.03125f;  // 1024^-0.5
  const int nkb = q0 / 32 + 2;
  for (int kbk = 0; kbk < nkb; kbk++) {
    f32x4 s[4][2] = {};
#pragma unroll
    for (int ks = 0; ks < 2; ks++) {
      bf16x8 kf[2];
#pragma unroll
      for (int n = 0; n < 2; n++)
        kf[n] = *(const bf16x8*)(kb + (kbk * 32 + n * 16 + lr) * 64 + ks * 32 + g * 8);
#pragma unroll
      for (int m = 0; m < 4; m++)
#pragma unroll
        for (int n = 0; n < 2; n++)
          s[m][n] = __builtin_amdgcn_mfma_f32_16x16x32_bf16(qf[m][ks], kf[n], s[m][n], 0, 0, 0);
    }
#pragma unroll
    for (int m = 0; m < 4; m++)
#pragma unroll
      for (int n = 0; n < 2; n++)
#pragma unroll
        for (int r = 0; r < 4; r++) {
          int row = q0 + m * 16 + g * 4 + r;
          int col = kbk * 32 + n * 16 + lr;
          float v = s[m][n][r] * scale;
          s[m][n][r] = (col <= row) ? v : -1e30f;
        }
#pragma unroll
    for (int m = 0; m < 4; m++)
#pragma unroll
      for (int r = 0; r < 4; r++) {
        float mx = fmaxf(s[m][0][r], s[m][1][r]);
#pragma unroll
        for (int off = 8; off; off >>= 1) mx = fmaxf(mx, __shfl_xor(mx, off));
        float mn = fmaxf(mrow[m][r], mx);
        float alpha = __expf(mrow[m][r] - mn);
        mrow[m][r] = mn;
        float rs = 0.0f;
#pragma unroll
        for (int n = 0; n < 2; n++) {
          float p = __expf(s[m][n][r] - mn);
          s[m][n][r] = p;
          rs += p;
        }
#pragma unroll
        for (int off = 8; off; off >>= 1) rs += __shfl_xor(rs, off);
        lrow[m][r] = lrow[m][r] * alpha + rs;
#pragma unroll
        for (int n = 0; n < 4; n++) o[m][n][r] *= alpha;
      }
#pragma unroll
    for (int m = 0; m < 4; m++)
#pragma unroll
      for (int n = 0; n < 2; n++)
#pragma unroll
        for (int r = 0; r < 4; r++)
          Ps[m * 16 + g * 4 + r][n * 16 + lr] = f2bf(s[m][n][r]);
    __syncthreads();
    bf16x8 vf[4];
#pragma unroll
    for (int n = 0; n < 4; n++)
      vf[n] = *(const bf16x8*)(vb + (n * 16 + lr) * 256 + kbk * 32 + g * 8);
#pragma unroll
    for (int m = 0; m < 4; m++) {
      bf16x8 pa = *(const bf16x8*)&Ps[m * 16 + lr][g * 8];
#pragma unroll
      for (int n = 0; n < 4; n++)
        o[m][n] = __builtin_amdgcn_mfma_f32_16x16x32_bf16(pa, vf[n], o[m][n], 0, 0, 0);
    }
    __syncthreads();
  }
#pragma unroll
  for (int m = 0; m < 4; m++)
#pragma unroll
    for (int r = 0; r < 4; r++) {
      float inv = 1.0f / lrow[m][r];
      long t = q0 + m * 16 + g * 4 + r;
#pragma unroll
      for (int n = 0; n < 4; n++) {
        long e = n * 16 + lr;
        ao[((long)bb * 256 + t) * 1024 + hh * 64 + e] = f2bf(o[m][n][r] * inv);
      }
    }
}

// ---------------- launch ---------------------------------------------------
// Workspace map (MB offsets, 184 MB): wqt@0 wkt@2 wvt@4 wpt@6 w1t@8 w2t@16
//   hb@24 (bf16 h / h2); X@56: qbf@56 kbf@88 vtb@120 atb@152; ff1 aliases @56.
// fp32 residual stream (h -> y -> h2 -> out) lives IN d_out.
extern "C" void kernel_launch(void* const* d_in, const int* in_sizes, int n_in,
                              void* d_out, int out_size, void* d_ws, size_t ws_size,
                              hipStream_t stream) {
  const float* x     = (const float*)d_in[0];
  const float* ln1g  = (const float*)d_in[1];
  const float* ln1b  = (const float*)d_in[2];
  const float* Wq    = (const float*)d_in[3];
  const float* Wk    = (const float*)d_in[4];
  const float* Wv    = (const float*)d_in[5];
  const float* Wproj = (const float*)d_in[6];
  const float* bproj = (const float*)d_in[7];
  const float* ln2g  = (const float*)d_in[8];
  const float* ln2b  = (const float*)d_in[9];
  const float* W1    = (const float*)d_in[10];
  const float* b1    = (const float*)d_in[11];
  const float* W2    = (const float*)d_in[12];
  const float* b2    = (const float*)d_in[13];

  const long NEED = 184L << 20;
  if (ws_size < (size_t)NEED) {
    fill_k<<<(out_size + 255) / 256, 256, 0, stream>>>((float*)d_out, out_size,
                                                       (float)(ws_size >> 20));
    return;
  }

  char* ws = (char*)d_ws;
  const long MB = 1 << 20;
  ushort_t* wqt = (ushort_t*)(ws + 0 * MB);
  ushort_t* wkt = (ushort_t*)(ws + 2 * MB);
  ushort_t* wvt = (ushort_t*)(ws + 4 * MB);
  ushort_t* wpt = (ushort_t*)(ws + 6 * MB);
  ushort_t* w1t = (ushort_t*)(ws + 8 * MB);
  ushort_t* w2t = (ushort_t*)(ws + 16 * MB);
  ushort_t* hb  = (ushort_t*)(ws + 24 * MB);
  ushort_t* qbf = (ushort_t*)(ws + 56 * MB);
  ushort_t* kbf = (ushort_t*)(ws + 88 * MB);
  ushort_t* vtb = (ushort_t*)(ws + 120 * MB);
  ushort_t* atb = (ushort_t*)(ws + 152 * MB);
  ushort_t* ff1 = (ushort_t*)(ws + 56 * MB);
  float*    yf  = (float*)d_out;

  transpose_w<<<dim3(32, 2, 16), 256, 0, stream>>>(Wq, wqt, 1024, 64);
  transpose_w<<<dim3(32, 2, 16), 256, 0, stream>>>(Wk, wkt, 1024, 64);
  transpose_w<<<dim3(32, 2, 16), 256, 0, stream>>>(Wv, wvt, 1024, 64);
  transpose_w<<<dim3(32, 32, 1), 256, 0, stream>>>(Wproj, wpt, 1024, 1024);
  transpose_w<<<dim3(32, 128, 1), 256, 0, stream>>>(W1, w1t, 1024, 4096);
  transpose_w<<<dim3(128, 32, 1), 256, 0, stream>>>(W2, w2t, 4096, 1024);

  ln_k<<<16384, 256, 0, stream>>>(x, ln1g, ln1b, yf, hb);
  // q/k/v projections (M=16384, N=1024, K=1024; grid 64x4=256)
  gemm256<0><<<256, 512, 0, stream>>>(hb, wqt, 16384, 1024, 1024, 4, nullptr, nullptr, nullptr, qbf);
  gemm256<0><<<256, 512, 0, stream>>>(hb, wkt, 16384, 1024, 1024, 4, nullptr, nullptr, nullptr, kbf);
  gemm256<1><<<256, 512, 0, stream>>>(hb, wvt, 16384, 1024, 1024, 4, nullptr, nullptr, nullptr, vtb);
  attn_k<<<4096, 64, 0, stream>>>(qbf, kbf, vtb, atb);
  // y = h + attn @ Wproj + bproj
  gemm256<2><<<256, 512, 0, stream>>>(atb, wpt, 16384, 1024, 1024, 4, bproj, yf, yf, nullptr);
  ln_k<<<16384, 256, 0, stream>>>(yf, ln2g, ln2b, yf, hb);
  // ff1 = relu(h2 @ W1 + b1)  (N=4096; grid 64x16=1024)
  gemm256<3><<<1024, 512, 0, stream>>>(hb, w1t, 16384, 4096, 1024, 16, b1, nullptr, nullptr, ff1);
  // out = h2 + ff1 @ W2 + b2  (K=4096)
  gemm256<2><<<256, 512, 0, stream>>>(ff1, w2t, 16384, 1024, 4096, 4, b2, yf, yf, nullptr);
}